// Round 6
// baseline (993.855 us; speedup 1.0000x reference)
//
#include <hip/hip_runtime.h>
#include <hip/hip_bf16.h>

#define NN 20000
#define NE 100000
#define NGR 64

using bf16 = __hip_bfloat16;
typedef __attribute__((ext_vector_type(8))) short v8s;
typedef __attribute__((ext_vector_type(4))) float v4f;

__device__ __forceinline__ float ldf(const void* p, int idx, int isbf) {
  if (isbf) return __bfloat162float(((const bf16*)p)[idx]);
  return ((const float*)p)[idx];
}
__device__ __forceinline__ unsigned short f2bfbits(float v) {
  unsigned int b = __float_as_uint(v);
  b += 0x7fffu + ((b >> 16) & 1u);
  return (unsigned short)(b >> 16);
}

// ---------------- dtype detector: 1 wave, writes flag (1=bf16, 0=f32) ----
__global__ __launch_bounds__(64) void k_detect(const unsigned short* __restrict__ xr,
                                               int* __restrict__ flag) {
  const int t = threadIdx.x;
  int cnt = 0;
#pragma unroll
  for (int j = 0; j < 4; j++) {
    unsigned short w = xr[t * 4 + j];
    int ex = (w >> 7) & 0xFF;
    cnt += (ex >= 118 && ex <= 131) ? 1 : 0;
  }
#pragma unroll
  for (int m = 32; m >= 1; m >>= 1) cnt += __shfl_xor(cnt, m, 64);
  if (t == 0) *flag = (cnt >= 192) ? 1 : 0;
}

// ---------------- degree histogram ----------------
__global__ __launch_bounds__(256) void k_deg(const int* __restrict__ ei,
                                             int* __restrict__ deg_src,
                                             int* __restrict__ deg_in) {
  int e = blockIdx.x * 256 + threadIdx.x;
  if (e < NE) {
    atomicAdd(&deg_src[ei[e]], 1);
    atomicAdd(&deg_in[ei[NE + e]], 1);
  }
}

// ---------------- single-block exclusive scan, 256 threads x 80 ----------
__global__ __launch_bounds__(256) void k_scan(const int* __restrict__ deg,
                                              int* __restrict__ off,
                                              int* __restrict__ cur) {
  constexpr int T = 256, CH = 80;  // 256*80 = 20480 >= NN
  __shared__ int sums[T];
  const int t = threadIdx.x;
  const int base = t * CH;
  int s = 0;
  for (int j = 0; j < CH; j++) {
    int i = base + j;
    s += (i < NN) ? deg[i] : 0;
  }
  sums[t] = s;
  __syncthreads();
  for (int st = 1; st < T; st <<= 1) {
    int v = (t >= st) ? sums[t - st] : 0;
    __syncthreads();
    sums[t] += v;
    __syncthreads();
  }
  int run = sums[t] - s;
  for (int j = 0; j < CH; j++) {
    int i = base + j;
    if (i < NN) {
      int v = deg[i];
      off[i] = run;
      cur[i] = run;
      run += v;
    }
  }
  if (t == T - 1) off[NN] = sums[T - 1];
}

// ---------------- CSR scatter ----------------
__global__ __launch_bounds__(256) void k_scatter(const int* __restrict__ ei,
                                                 int* __restrict__ cur,
                                                 int* __restrict__ ebs) {
  int e = blockIdx.x * 256 + threadIdx.x;
  if (e < NE) {
    int p = atomicAdd(&cur[ei[e]], 1);
    if (p >= 0 && p < NE) ebs[p] = e;
  }
}

// -------- W2(+eb2 bias row) -> MFMA B-fragment pre-shuffle ---------------
// k-slot layout: k2 < KH -> W2 row k2; k2 == KH -> eb2; k2 > KH -> 0.
// Fragment F=(k2*4+ot)*2+ks holds B[i][o2]: i=ks*32+(lane>>4)*8+j (0 if >=IN),
// o2=ot*16+(lane&15). Grid: KSLOT*2 blocks of 256.
template <int KH, int IN, int KSLOT>
__global__ __launch_bounds__(256) void k_shuffle(const void* __restrict__ W2,
                                                 const void* __restrict__ eb2,
                                                 unsigned short* __restrict__ W2s,
                                                 const int* __restrict__ flag) {
  const int f = *flag;
  int t = blockIdx.x * 256 + threadIdx.x;
  int lane = t & 63, F = t >> 6;
  int ks = F & 1, ot = (F >> 1) & 3, k2 = F >> 3;
  if (k2 >= KSLOT) return;
  int q = lane >> 4, col = lane & 15;
  unsigned short tmp[8];
#pragma unroll
  for (int j = 0; j < 8; j++) {
    int i = ks * 32 + q * 8 + j;
    float v = 0.f;
    if (i < IN) {
      if (k2 < KH) v = ldf(W2, k2 * (IN * 64) + i * 64 + ot * 16 + col, f);
      else if (k2 == KH) v = ldf(eb2, i * 64 + ot * 16 + col, f);
    }
    tmp[j] = f2bfbits(v);
  }
  *(uint4*)(W2s + (size_t)F * 512 + lane * 8) = *(uint4*)tmp;
}

// ---------------- wave-independent fused NNConv, k-split ----------------
// Block bid: node-group g = bid/KSPLIT, k-range split = bid%KSPLIT.
// Wave owns NPW=8 nodes + their CSR edges; chunks [c0,c1) of 4 k-slots.
// Per chunk: MFMA Q-chunk -> wave-private f32 LDS; z per edge in regs;
// branchless message loop (ds_read_b128 + readlane-z). Partial messages
// atomically added to agg (k-splits sum via atomics). No in-loop barriers.
// NOTE: no `break` in unrolled loops (round-4 scratch-spill lesson).
template <int IN, int KH, int KSLOT, int HMODE, int KSPLIT>
__global__ __launch_bounds__(256, 3) void k_fused4(
    const void* __restrict__ h_in, const void* __restrict__ eW1,
    const void* __restrict__ eb1, const unsigned short* __restrict__ W2s,
    const void* __restrict__ ea, const int* __restrict__ ei,
    const int* __restrict__ src_off, const int* __restrict__ ebs,
    float* __restrict__ agg, const int* __restrict__ flag) {
  constexpr int NPW = 8;          // nodes per wave
  constexpr int NCH = KSLOT / 4;  // total 4-k-slot chunks
  constexpr int EW = 48;          // edge window (msg registers)
  constexpr int QS = 260;         // Qc node stride (floats), pad vs 256

  __shared__ float eW1S[5 * KSLOT];  // rows 0..3: eW1; row 4: eb1
  __shared__ __align__(16) float QcS[4][NPW * QS];

  const int f = *flag;
  const int tid = threadIdx.x;
  const int lane = tid & 63;
  const int wid = tid >> 6;
  const int bid = blockIdx.x;
  const int g = bid / KSPLIT;
  const int split = bid - g * KSPLIT;
  const int n0 = g * (4 * NPW) + wid * NPW;
  const int c0 = (NCH * split) / KSPLIT;
  const int c1 = (NCH * (split + 1)) / KSPLIT;

  for (int idx = tid; idx < 5 * KSLOT; idx += 256) {
    int r = idx / KSLOT, k = idx - r * KSLOT;
    float v = 0.f;
    if (k < KH) v = (r < 4) ? ldf(eW1, r * KH + k, f) : ldf(eb1, k, f);
    eW1S[idx] = v;
  }
  __syncthreads();  // only barrier in the kernel

  float* __restrict__ Qc = &QcS[wid][0];

  // ---- A fragments, once per wave: A[m][k] m=lane&15, k=(lane>>4)*8+j ----
  const int am = lane & 15, aq = lane >> 4;
  v8s aF0, aF1;
  {
    union { unsigned short u[8]; v8s v; } u0, u1;
#pragma unroll
    for (int j = 0; j < 8; j++) {
      int k0 = aq * 8 + j, k1 = 32 + aq * 8 + j;
      float v0 = 0.f, v1 = 0.f;
      if (am < NPW) {
        int node = n0 + am;
        if (k0 < IN)
          v0 = HMODE ? ((const float*)h_in)[node * IN + k0]
                     : ldf(h_in, node * IN + k0, f);
        if (k1 < IN)
          v1 = HMODE ? ((const float*)h_in)[node * IN + k1]
                     : ldf(h_in, node * IN + k1, f);
      }
      u0.u[j] = f2bfbits(v0);
      u1.u[j] = f2bfbits(v1);
    }
    aF0 = u0.v;
    aF1 = u1.v;
  }

  const int estart = src_off[n0];
  const int ecount = src_off[n0 + NPW] - estart;
  const int o = lane;

  for (int w0 = 0; w0 < ecount; w0 += EW) {
    const int wcnt = min(EW, ecount - w0);
    int esrcR = 0, edstR = 0;
    float eaR[4] = {0.f, 0.f, 0.f, 0.f};
    if (lane < wcnt) {
      int eid = ebs[estart + w0 + lane];
      esrcR = ei[eid] - n0;
      edstR = ei[NE + eid];
#pragma unroll
      for (int i = 0; i < 4; i++) eaR[i] = ldf(ea, eid * 4 + i, f);
    }
    float msg[EW];
#pragma unroll
    for (int j = 0; j < EW; j++) msg[j] = 0.f;

    for (int c = c0; c < c1; c++) {
      // ---- z for MY edge, 4 k's, packed bf16 in registers ----
      uint2 zpak;
      {
        float zv[4];
#pragma unroll
        for (int kk = 0; kk < 4; kk++) {
          int k = c * 4 + kk;
          float v;
          if (k < KH) {
            float a = eW1S[4 * KSLOT + k];
#pragma unroll
            for (int i = 0; i < 4; i++) a += eaR[i] * eW1S[i * KSLOT + k];
            v = fmaxf(a, 0.f);
          } else {
            v = (k == KH) ? 1.f : 0.f;
          }
          zv[kk] = v;
        }
        zpak.x = (unsigned)f2bfbits(zv[0]) | ((unsigned)f2bfbits(zv[1]) << 16);
        zpak.y = (unsigned)f2bfbits(zv[2]) | ((unsigned)f2bfbits(zv[3]) << 16);
      }
      // ---- Q chunk by MFMA, two halves of 2 k-slots; spill f32 to Qc ----
#pragma unroll
      for (int h = 0; h < 2; h++) {
        v4f acc[2][4];
#pragma unroll
        for (int kl = 0; kl < 2; kl++) {
#pragma unroll
          for (int og = 0; og < 4; og++) {
            acc[kl][og] = (v4f){0.f, 0.f, 0.f, 0.f};
            const int k2 = c * 4 + h * 2 + kl;
            const size_t Fb = (size_t)((k2 * 4 + og) * 2);
            v8s b0 = *(const v8s*)(W2s + Fb * 512 + lane * 8);
            acc[kl][og] = __builtin_amdgcn_mfma_f32_16x16x32_bf16(
                aF0, b0, acc[kl][og], 0, 0, 0);
            if (IN > 32) {
              v8s b1 = *(const v8s*)(W2s + (Fb + 1) * 512 + lane * 8);
              acc[kl][og] = __builtin_amdgcn_mfma_f32_16x16x32_bf16(
                  aF1, b1, acc[kl][og], 0, 0, 0);
            }
          }
        }
        if (aq < 2) {  // nodes 0..7 live in quads 0,1; rows = aq*4+r
#pragma unroll
          for (int r = 0; r < 4; r++) {
#pragma unroll
            for (int og = 0; og < 4; og++) {
              int n = aq * 4 + r;
              int o2 = og * 16 + am;
              float2 pk = make_float2(acc[0][og][r], acc[1][og][r]);
              *(float2*)(Qc + n * QS + o2 * 4 + h * 2) = pk;
            }
          }
        }
      }
      // ---- branchless message loop: all EW slots, garbage never flushed --
#pragma unroll
      for (int j = 0; j < EW; j++) {
        const int s = __shfl(esrcR, j);  // readlane broadcast
        const v4f qq = *(const v4f*)(Qc + s * QS + o * 4);
        const unsigned zx = __shfl(zpak.x, j);
        const unsigned zy = __shfl(zpak.y, j);
        float m = msg[j];
        m += __uint_as_float(zx << 16) * qq[0];
        m += __uint_as_float(zx & 0xffff0000u) * qq[1];
        m += __uint_as_float(zy << 16) * qq[2];
        m += __uint_as_float(zy & 0xffff0000u) * qq[3];
        msg[j] = m;
      }
    }  // chunks
    // ---- flush window (guarded; k-split partials sum via atomics) ----
#pragma unroll
    for (int j = 0; j < EW; j++) {
      if (j < wcnt) {
        int dst = __shfl(edstR, j);
        atomicAdd(&agg[(size_t)dst * 64 + o], msg[j]);
      }
    }
  }  // windows
}

// ---------------- wave-wide sum over 64 lanes ----------------
__device__ __forceinline__ float wave_sum(float v) {
#pragma unroll
  for (int m = 32; m >= 1; m >>= 1) v += __shfl_xor(v, m, 64);
  return v;
}

// ---------------- node update 1: h1 = LN(relu(agg/deg + x@root1 + bias1)) -
__global__ __launch_bounds__(256) void k_node1(
    const float* __restrict__ agg1, const int* __restrict__ deg_in,
    const void* __restrict__ x, const void* __restrict__ root1,
    const void* __restrict__ bias1, const void* __restrict__ g1,
    const void* __restrict__ b1, float* __restrict__ h1,
    const int* __restrict__ flag) {
  const int f = *flag;
  const int n = blockIdx.x * 4 + (threadIdx.x >> 6);
  const int o = threadIdx.x & 63;
  float v = agg1[n * 64 + o] / fmaxf((float)deg_in[n], 1.f);
#pragma unroll
  for (int i = 0; i < 4; i++) v += ldf(x, n * 4 + i, f) * ldf(root1, i * 64 + o, f);
  v += ldf(bias1, o, f);
  v = fmaxf(v, 0.f);
  const float mu = wave_sum(v) * (1.f / 64.f);
  const float d = v - mu;
  const float var = wave_sum(d * d) * (1.f / 64.f);
  h1[n * 64 + o] = d * rsqrtf(var + 1e-5f) * ldf(g1, o, f) + ldf(b1, o, f);
}

// ---------------- node update 2 + pooled accumulation ----------------
__global__ __launch_bounds__(256) void k_node2(
    const float* __restrict__ agg2, const int* __restrict__ deg_in,
    const float* __restrict__ h1, const void* __restrict__ root2,
    const void* __restrict__ bias2, const void* __restrict__ g2,
    const void* __restrict__ b2, const int* __restrict__ batch,
    float* __restrict__ psum, float* __restrict__ pcnt,
    const int* __restrict__ flag) {
  const int f = *flag;
  const int n = blockIdx.x * 4 + (threadIdx.x >> 6);
  const int o = threadIdx.x & 63;
  float v = agg2[n * 64 + o] / fmaxf((float)deg_in[n], 1.f);
  const float* hrow = h1 + (size_t)n * 64;
  for (int i = 0; i < 64; i++) v += hrow[i] * ldf(root2, i * 64 + o, f);
  v += ldf(bias2, o, f);
  v = fmaxf(v, 0.f);
  const float mu = wave_sum(v) * (1.f / 64.f);
  const float d = v - mu;
  const float var = wave_sum(d * d) * (1.f / 64.f);
  const float out = d * rsqrtf(var + 1e-5f) * ldf(g2, o, f) + ldf(b2, o, f);
  const int bi = batch[n];
  atomicAdd(&psum[bi * 64 + o], out);
  if (o == 0) atomicAdd(&pcnt[bi], 1.f);
}

// ---------------- final mean + dtype-flagged output ----------------
__global__ __launch_bounds__(256) void k_out(const float* __restrict__ psum,
                                             const float* __restrict__ pcnt,
                                             void* __restrict__ out,
                                             const int* __restrict__ flag) {
  const int idx = blockIdx.x * 256 + threadIdx.x;  // 4096 total
  float v = psum[idx] / fmaxf(pcnt[idx >> 6], 1.f);
  if (*flag)
    ((bf16*)out)[idx] = __float2bfloat16(v);
  else
    ((float*)out)[idx] = v;
}

extern "C" void kernel_launch(void* const* d_in, const int* in_sizes, int n_in,
                              void* d_out, int out_size, void* d_ws,
                              size_t ws_size, hipStream_t stream) {
  (void)in_sizes; (void)n_in; (void)out_size; (void)ws_size;
  const void* x = d_in[0];
  const int* ei = (const int*)d_in[1];
  const void* ea = d_in[2];
  const int* batch = (const int*)d_in[3];
  const void* eW1_1 = d_in[4];
  const void* eb1_1 = d_in[5];
  const void* eW2_1 = d_in[6];
  const void* eb2_1 = d_in[7];
  const void* root1 = d_in[8];
  const void* bias1 = d_in[9];
  const void* g1 = d_in[10];
  const void* b1 = d_in[11];
  const void* eW1_2 = d_in[12];
  const void* eb1_2 = d_in[13];
  const void* eW2_2 = d_in[14];
  const void* eb2_2 = d_in[15];
  const void* root2 = d_in[16];
  const void* bias2 = d_in[17];
  const void* g2 = d_in[18];
  const void* b2 = d_in[19];

  char* w = (char*)d_ws;
  size_t off = 0;
  auto alloc = [&](size_t bytes) -> void* {
    void* p = w + off;
    off = (off + bytes + 255) & ~(size_t)255;
    return p;
  };
  float* agg1 = (float*)alloc((size_t)NN * 64 * 4);
  float* agg2 = (float*)alloc((size_t)NN * 64 * 4);
  float* psum = (float*)alloc((size_t)NGR * 64 * 4);
  float* pcnt = (float*)alloc((size_t)NGR * 4);
  int* deg_src = (int*)alloc((size_t)NN * 4);
  int* deg_in = (int*)alloc((size_t)NN * 4);
  const size_t zero_bytes = off;  // everything above must start at 0
  int* src_off = (int*)alloc((size_t)(NN + 1) * 4);
  int* cur = (int*)alloc((size_t)NN * 4);
  int* ebs = (int*)alloc((size_t)NE * 4);
  int* flag = (int*)alloc(256);
  float* h1 = (float*)alloc((size_t)NN * 64 * 4);
  unsigned short* W2s1 = (unsigned short*)alloc((size_t)68 * 8 * 512 * 2);
  unsigned short* W2s2 = (unsigned short*)alloc((size_t)132 * 8 * 512 * 2);

  hipMemsetAsync(d_ws, 0, zero_bytes, stream);

  k_detect<<<1, 64, 0, stream>>>((const unsigned short*)x, flag);
  k_deg<<<(NE + 255) / 256, 256, 0, stream>>>(ei, deg_src, deg_in);
  k_scan<<<1, 256, 0, stream>>>(deg_src, src_off, cur);
  k_scatter<<<(NE + 255) / 256, 256, 0, stream>>>(ei, cur, ebs);
  k_shuffle<64, 4, 68><<<68 * 2, 256, 0, stream>>>(eW2_1, eb2_1, W2s1, flag);
  k_shuffle<128, 64, 132><<<132 * 2, 256, 0, stream>>>(eW2_2, eb2_2, W2s2, flag);
  k_fused4<4, 64, 68, 0, 2><<<(NN / 32) * 2, 256, 0, stream>>>(
      x, eW1_1, eb1_1, W2s1, ea, ei, src_off, ebs, agg1, flag);
  k_node1<<<NN / 4, 256, 0, stream>>>(agg1, deg_in, x, root1, bias1, g1, b1,
                                      h1, flag);
  k_fused4<64, 128, 132, 1, 3><<<(NN / 32) * 3, 256, 0, stream>>>(
      h1, eW1_2, eb1_2, W2s2, ea, ei, src_off, ebs, agg2, flag);
  k_node2<<<NN / 4, 256, 0, stream>>>(agg2, deg_in, h1, root2, bias2, g2, b2,
                                      batch, psum, pcnt, flag);
  k_out<<<(NGR * 64) / 256, 256, 0, stream>>>(psum, pcnt, d_out, flag);
}

// Round 7
// 818.254 us; speedup vs baseline: 1.2146x; 1.2146x over previous
//
#include <hip/hip_runtime.h>
#include <hip/hip_bf16.h>

#define NN 20000
#define NE 100000
#define NGR 64

using bf16 = __hip_bfloat16;
typedef __attribute__((ext_vector_type(8))) short v8s;
typedef __attribute__((ext_vector_type(4))) float v4f;

__device__ __forceinline__ float ldf(const void* p, int idx, int isbf) {
  if (isbf) return __bfloat162float(((const bf16*)p)[idx]);
  return ((const float*)p)[idx];
}
__device__ __forceinline__ unsigned short f2bfbits(float v) {
  unsigned int b = __float_as_uint(v);
  b += 0x7fffu + ((b >> 16) & 1u);
  return (unsigned short)(b >> 16);
}
// wave-uniform broadcast WITHOUT the LDS crossbar (ds_bpermute):
__device__ __forceinline__ int rdlane(int v, int l) {
  return __builtin_amdgcn_readlane(v, l);
}
__device__ __forceinline__ unsigned rdlaneu(unsigned v, int l) {
  return (unsigned)__builtin_amdgcn_readlane((int)v, l);
}

// ---------------- dtype detector: 1 wave, writes flag (1=bf16, 0=f32) ----
__global__ __launch_bounds__(64) void k_detect(const unsigned short* __restrict__ xr,
                                               int* __restrict__ flag) {
  const int t = threadIdx.x;
  int cnt = 0;
#pragma unroll
  for (int j = 0; j < 4; j++) {
    unsigned short w = xr[t * 4 + j];
    int ex = (w >> 7) & 0xFF;
    cnt += (ex >= 118 && ex <= 131) ? 1 : 0;
  }
#pragma unroll
  for (int m = 32; m >= 1; m >>= 1) cnt += __shfl_xor(cnt, m, 64);
  if (t == 0) *flag = (cnt >= 192) ? 1 : 0;
}

// ---------------- degree histogram ----------------
__global__ __launch_bounds__(256) void k_deg(const int* __restrict__ ei,
                                             int* __restrict__ deg_src,
                                             int* __restrict__ deg_in) {
  int e = blockIdx.x * 256 + threadIdx.x;
  if (e < NE) {
    atomicAdd(&deg_src[ei[e]], 1);
    atomicAdd(&deg_in[ei[NE + e]], 1);
  }
}

// ---------------- single-block exclusive scan, 256 threads x 80 ----------
__global__ __launch_bounds__(256) void k_scan(const int* __restrict__ deg,
                                              int* __restrict__ off,
                                              int* __restrict__ cur) {
  constexpr int T = 256, CH = 80;  // 256*80 = 20480 >= NN
  __shared__ int sums[T];
  const int t = threadIdx.x;
  const int base = t * CH;
  int s = 0;
  for (int j = 0; j < CH; j++) {
    int i = base + j;
    s += (i < NN) ? deg[i] : 0;
  }
  sums[t] = s;
  __syncthreads();
  for (int st = 1; st < T; st <<= 1) {
    int v = (t >= st) ? sums[t - st] : 0;
    __syncthreads();
    sums[t] += v;
    __syncthreads();
  }
  int run = sums[t] - s;
  for (int j = 0; j < CH; j++) {
    int i = base + j;
    if (i < NN) {
      int v = deg[i];
      off[i] = run;
      cur[i] = run;
      run += v;
    }
  }
  if (t == T - 1) off[NN] = sums[T - 1];
}

// ---------------- CSR scatter ----------------
__global__ __launch_bounds__(256) void k_scatter(const int* __restrict__ ei,
                                                 int* __restrict__ cur,
                                                 int* __restrict__ ebs) {
  int e = blockIdx.x * 256 + threadIdx.x;
  if (e < NE) {
    int p = atomicAdd(&cur[ei[e]], 1);
    if (p >= 0 && p < NE) ebs[p] = e;
  }
}

// -------- W2(+eb2 bias row) -> MFMA B-fragment pre-shuffle ---------------
// k-slot layout: k2 < KH -> W2 row k2; k2 == KH -> eb2; k2 > KH -> 0.
// Fragment F=(k2*4+ot)*2+ks holds B[i][o2]: i=ks*32+(lane>>4)*8+j (0 if >=IN),
// o2=ot*16+(lane&15). Grid: KSLOT*2 blocks of 256.
template <int KH, int IN, int KSLOT>
__global__ __launch_bounds__(256) void k_shuffle(const void* __restrict__ W2,
                                                 const void* __restrict__ eb2,
                                                 unsigned short* __restrict__ W2s,
                                                 const int* __restrict__ flag) {
  const int f = *flag;
  int t = blockIdx.x * 256 + threadIdx.x;
  int lane = t & 63, F = t >> 6;
  int ks = F & 1, ot = (F >> 1) & 3, k2 = F >> 3;
  if (k2 >= KSLOT) return;
  int q = lane >> 4, col = lane & 15;
  unsigned short tmp[8];
#pragma unroll
  for (int j = 0; j < 8; j++) {
    int i = ks * 32 + q * 8 + j;
    float v = 0.f;
    if (i < IN) {
      if (k2 < KH) v = ldf(W2, k2 * (IN * 64) + i * 64 + ot * 16 + col, f);
      else if (k2 == KH) v = ldf(eb2, i * 64 + ot * 16 + col, f);
    }
    tmp[j] = f2bfbits(v);
  }
  *(uint4*)(W2s + (size_t)F * 512 + lane * 8) = *(uint4*)tmp;
}

// ---------------- wave-independent fused NNConv, k-split ----------------
// Block bid: node-group g = bid/KSPLIT, k-range split = bid%KSPLIT.
// Wave owns NPW=8 nodes + their CSR edges; chunks [c0,c1) of 4 k-slots.
// Per chunk: MFMA Q-chunk -> wave-private bf16-packed LDS; z per edge in
// regs; message loop uses v_readlane broadcasts (NO ds_bpermute) + one
// ds_read_b64 per edge. No in-loop barriers, no break in unrolled loops.
template <int IN, int KH, int KSLOT, int HMODE, int KSPLIT>
__global__ __launch_bounds__(256, 3) void k_fused5(
    const void* __restrict__ h_in, const void* __restrict__ eW1,
    const void* __restrict__ eb1, const unsigned short* __restrict__ W2s,
    const void* __restrict__ ea, const int* __restrict__ ei,
    const int* __restrict__ src_off, const int* __restrict__ ebs,
    float* __restrict__ agg, const int* __restrict__ flag) {
  constexpr int NPW = 8;          // nodes per wave
  constexpr int NCH = KSLOT / 4;  // total 4-k-slot chunks
  constexpr int EW = 48;          // edge window (msg registers)

  __shared__ float eW1S[5 * KSLOT];  // rows 0..3: eW1; row 4: eb1
  // Qc: per wave, node n, output o: uint2 = 4 bf16 (k-slots of chunk)
  __shared__ __align__(16) unsigned int QcS[4][NPW * 128];

  const int f = *flag;
  const int tid = threadIdx.x;
  const int lane = tid & 63;
  const int wid = tid >> 6;
  const int bid = blockIdx.x;
  const int g = bid / KSPLIT;
  const int split = bid - g * KSPLIT;
  const int n0 = g * (4 * NPW) + wid * NPW;
  const int c0 = (NCH * split) / KSPLIT;
  const int c1 = (NCH * (split + 1)) / KSPLIT;

  for (int idx = tid; idx < 5 * KSLOT; idx += 256) {
    int r = idx / KSLOT, k = idx - r * KSLOT;
    float v = 0.f;
    if (k < KH) v = (r < 4) ? ldf(eW1, r * KH + k, f) : ldf(eb1, k, f);
    eW1S[idx] = v;
  }
  __syncthreads();  // only barrier in the kernel

  unsigned int* __restrict__ Qc = &QcS[wid][0];

  // ---- A fragments, once per wave: A[m][k] m=lane&15, k=(lane>>4)*8+j ----
  const int am = lane & 15, aq = lane >> 4;
  v8s aF0, aF1;
  {
    union { unsigned short u[8]; v8s v; } u0, u1;
#pragma unroll
    for (int j = 0; j < 8; j++) {
      int k0 = aq * 8 + j, k1 = 32 + aq * 8 + j;
      float v0 = 0.f, v1 = 0.f;
      if (am < NPW) {
        int node = n0 + am;
        if (k0 < IN)
          v0 = HMODE ? ((const float*)h_in)[node * IN + k0]
                     : ldf(h_in, node * IN + k0, f);
        if (k1 < IN)
          v1 = HMODE ? ((const float*)h_in)[node * IN + k1]
                     : ldf(h_in, node * IN + k1, f);
      }
      u0.u[j] = f2bfbits(v0);
      u1.u[j] = f2bfbits(v1);
    }
    aF0 = u0.v;
    aF1 = u1.v;
  }

  const int estart = src_off[n0];
  const int ecount = src_off[n0 + NPW] - estart;
  const int o = lane;

  for (int w0 = 0; w0 < ecount; w0 += EW) {
    const int wcnt = min(EW, ecount - w0);
    int esrcR = 0, edstR = 0;
    float eaR[4] = {0.f, 0.f, 0.f, 0.f};
    if (lane < wcnt) {
      int eid = ebs[estart + w0 + lane];
      esrcR = ei[eid] - n0;
      edstR = ei[NE + eid];
#pragma unroll
      for (int i = 0; i < 4; i++) eaR[i] = ldf(ea, eid * 4 + i, f);
    }
    float msg[EW];
#pragma unroll
    for (int j = 0; j < EW; j++) msg[j] = 0.f;

    for (int c = c0; c < c1; c++) {
      // ---- z for MY edge, 4 k's, packed bf16 in registers ----
      uint2 zpak;
      {
        float zv[4];
#pragma unroll
        for (int kk = 0; kk < 4; kk++) {
          int k = c * 4 + kk;
          float v;
          if (k < KH) {
            float a = eW1S[4 * KSLOT + k];
#pragma unroll
            for (int i = 0; i < 4; i++) a += eaR[i] * eW1S[i * KSLOT + k];
            v = fmaxf(a, 0.f);
          } else {
            v = (k == KH) ? 1.f : 0.f;
          }
          zv[kk] = v;
        }
        zpak.x = (unsigned)f2bfbits(zv[0]) | ((unsigned)f2bfbits(zv[1]) << 16);
        zpak.y = (unsigned)f2bfbits(zv[2]) | ((unsigned)f2bfbits(zv[3]) << 16);
      }
      // ---- Q chunk by MFMA, two halves of 2 k-slots; spill bf16 to Qc ----
#pragma unroll
      for (int h = 0; h < 2; h++) {
        v4f acc[2][4];
#pragma unroll
        for (int kl = 0; kl < 2; kl++) {
#pragma unroll
          for (int og = 0; og < 4; og++) {
            acc[kl][og] = (v4f){0.f, 0.f, 0.f, 0.f};
            const int k2 = c * 4 + h * 2 + kl;
            const size_t Fb = (size_t)((k2 * 4 + og) * 2);
            v8s b0 = *(const v8s*)(W2s + Fb * 512 + lane * 8);
            acc[kl][og] = __builtin_amdgcn_mfma_f32_16x16x32_bf16(
                aF0, b0, acc[kl][og], 0, 0, 0);
            if (IN > 32) {
              v8s b1 = *(const v8s*)(W2s + (Fb + 1) * 512 + lane * 8);
              acc[kl][og] = __builtin_amdgcn_mfma_f32_16x16x32_bf16(
                  aF1, b1, acc[kl][og], 0, 0, 0);
            }
          }
        }
        if (aq < 2) {  // nodes 0..7 live in quads 0,1; rows = aq*4+r
#pragma unroll
          for (int r = 0; r < 4; r++) {
#pragma unroll
            for (int og = 0; og < 4; og++) {
              int n = aq * 4 + r;
              int o2 = og * 16 + am;
              unsigned int pk = (unsigned)f2bfbits(acc[0][og][r]) |
                                ((unsigned)f2bfbits(acc[1][og][r]) << 16);
              Qc[n * 128 + o2 * 2 + h] = pk;
            }
          }
        }
      }
      // ---- message loop: readlane broadcasts + one ds_read_b64 per edge --
#pragma unroll
      for (int j = 0; j < EW; j++) {
        const int s = rdlane(esrcR, j);         // SGPR, no LDS
        const unsigned zx = rdlaneu(zpak.x, j); // SGPR
        const unsigned zy = rdlaneu(zpak.y, j); // SGPR
        const uint2 qq = *(const uint2*)(Qc + s * 128 + o * 2);
        float m = msg[j];
        m += __uint_as_float(zx << 16) * __uint_as_float(qq.x << 16);
        m += __uint_as_float(zx & 0xffff0000u) *
             __uint_as_float(qq.x & 0xffff0000u);
        m += __uint_as_float(zy << 16) * __uint_as_float(qq.y << 16);
        m += __uint_as_float(zy & 0xffff0000u) *
             __uint_as_float(qq.y & 0xffff0000u);
        msg[j] = m;
      }
    }  // chunks
    // ---- flush window (guarded; k-split partials sum via atomics) ----
#pragma unroll
    for (int j = 0; j < EW; j++) {
      if (j < wcnt) {
        int dst = rdlane(edstR, j);
        atomicAdd(&agg[(size_t)dst * 64 + o], msg[j]);
      }
    }
  }  // windows
}

// ---------------- wave-wide sum over 64 lanes ----------------
__device__ __forceinline__ float wave_sum(float v) {
#pragma unroll
  for (int m = 32; m >= 1; m >>= 1) v += __shfl_xor(v, m, 64);
  return v;
}

// ---------------- node update 1: h1 = LN(relu(agg/deg + x@root1 + bias1)) -
__global__ __launch_bounds__(256) void k_node1(
    const float* __restrict__ agg1, const int* __restrict__ deg_in,
    const void* __restrict__ x, const void* __restrict__ root1,
    const void* __restrict__ bias1, const void* __restrict__ g1,
    const void* __restrict__ b1, float* __restrict__ h1,
    const int* __restrict__ flag) {
  const int f = *flag;
  const int n = blockIdx.x * 4 + (threadIdx.x >> 6);
  const int o = threadIdx.x & 63;
  float v = agg1[n * 64 + o] / fmaxf((float)deg_in[n], 1.f);
#pragma unroll
  for (int i = 0; i < 4; i++) v += ldf(x, n * 4 + i, f) * ldf(root1, i * 64 + o, f);
  v += ldf(bias1, o, f);
  v = fmaxf(v, 0.f);
  const float mu = wave_sum(v) * (1.f / 64.f);
  const float d = v - mu;
  const float var = wave_sum(d * d) * (1.f / 64.f);
  h1[n * 64 + o] = d * rsqrtf(var + 1e-5f) * ldf(g1, o, f) + ldf(b1, o, f);
}

// ---------------- node update 2 + pooled accumulation ----------------
__global__ __launch_bounds__(256) void k_node2(
    const float* __restrict__ agg2, const int* __restrict__ deg_in,
    const float* __restrict__ h1, const void* __restrict__ root2,
    const void* __restrict__ bias2, const void* __restrict__ g2,
    const void* __restrict__ b2, const int* __restrict__ batch,
    float* __restrict__ psum, float* __restrict__ pcnt,
    const int* __restrict__ flag) {
  const int f = *flag;
  const int n = blockIdx.x * 4 + (threadIdx.x >> 6);
  const int o = threadIdx.x & 63;
  float v = agg2[n * 64 + o] / fmaxf((float)deg_in[n], 1.f);
  const float* hrow = h1 + (size_t)n * 64;
  for (int i = 0; i < 64; i++) v += hrow[i] * ldf(root2, i * 64 + o, f);
  v += ldf(bias2, o, f);
  v = fmaxf(v, 0.f);
  const float mu = wave_sum(v) * (1.f / 64.f);
  const float d = v - mu;
  const float var = wave_sum(d * d) * (1.f / 64.f);
  const float out = d * rsqrtf(var + 1e-5f) * ldf(g2, o, f) + ldf(b2, o, f);
  const int bi = batch[n];
  atomicAdd(&psum[bi * 64 + o], out);
  if (o == 0) atomicAdd(&pcnt[bi], 1.f);
}

// ---------------- final mean + dtype-flagged output ----------------
__global__ __launch_bounds__(256) void k_out(const float* __restrict__ psum,
                                             const float* __restrict__ pcnt,
                                             void* __restrict__ out,
                                             const int* __restrict__ flag) {
  const int idx = blockIdx.x * 256 + threadIdx.x;  // 4096 total
  float v = psum[idx] / fmaxf(pcnt[idx >> 6], 1.f);
  if (*flag)
    ((bf16*)out)[idx] = __float2bfloat16(v);
  else
    ((float*)out)[idx] = v;
}

extern "C" void kernel_launch(void* const* d_in, const int* in_sizes, int n_in,
                              void* d_out, int out_size, void* d_ws,
                              size_t ws_size, hipStream_t stream) {
  (void)in_sizes; (void)n_in; (void)out_size; (void)ws_size;
  const void* x = d_in[0];
  const int* ei = (const int*)d_in[1];
  const void* ea = d_in[2];
  const int* batch = (const int*)d_in[3];
  const void* eW1_1 = d_in[4];
  const void* eb1_1 = d_in[5];
  const void* eW2_1 = d_in[6];
  const void* eb2_1 = d_in[7];
  const void* root1 = d_in[8];
  const void* bias1 = d_in[9];
  const void* g1 = d_in[10];
  const void* b1 = d_in[11];
  const void* eW1_2 = d_in[12];
  const void* eb1_2 = d_in[13];
  const void* eW2_2 = d_in[14];
  const void* eb2_2 = d_in[15];
  const void* root2 = d_in[16];
  const void* bias2 = d_in[17];
  const void* g2 = d_in[18];
  const void* b2 = d_in[19];

  char* w = (char*)d_ws;
  size_t off = 0;
  auto alloc = [&](size_t bytes) -> void* {
    void* p = w + off;
    off = (off + bytes + 255) & ~(size_t)255;
    return p;
  };
  float* agg1 = (float*)alloc((size_t)NN * 64 * 4);
  float* agg2 = (float*)alloc((size_t)NN * 64 * 4);
  float* psum = (float*)alloc((size_t)NGR * 64 * 4);
  float* pcnt = (float*)alloc((size_t)NGR * 4);
  int* deg_src = (int*)alloc((size_t)NN * 4);
  int* deg_in = (int*)alloc((size_t)NN * 4);
  const size_t zero_bytes = off;  // everything above must start at 0
  int* src_off = (int*)alloc((size_t)(NN + 1) * 4);
  int* cur = (int*)alloc((size_t)NN * 4);
  int* ebs = (int*)alloc((size_t)NE * 4);
  int* flag = (int*)alloc(256);
  float* h1 = (float*)alloc((size_t)NN * 64 * 4);
  unsigned short* W2s1 = (unsigned short*)alloc((size_t)68 * 8 * 512 * 2);
  unsigned short* W2s2 = (unsigned short*)alloc((size_t)132 * 8 * 512 * 2);

  hipMemsetAsync(d_ws, 0, zero_bytes, stream);

  k_detect<<<1, 64, 0, stream>>>((const unsigned short*)x, flag);
  k_deg<<<(NE + 255) / 256, 256, 0, stream>>>(ei, deg_src, deg_in);
  k_scan<<<1, 256, 0, stream>>>(deg_src, src_off, cur);
  k_scatter<<<(NE + 255) / 256, 256, 0, stream>>>(ei, cur, ebs);
  k_shuffle<64, 4, 68><<<68 * 2, 256, 0, stream>>>(eW2_1, eb2_1, W2s1, flag);
  k_shuffle<128, 64, 132><<<132 * 2, 256, 0, stream>>>(eW2_2, eb2_2, W2s2, flag);
  k_fused5<4, 64, 68, 0, 2><<<(NN / 32) * 2, 256, 0, stream>>>(
      x, eW1_1, eb1_1, W2s1, ea, ei, src_off, ebs, agg1, flag);
  k_node1<<<NN / 4, 256, 0, stream>>>(agg1, deg_in, x, root1, bias1, g1, b1,
                                      h1, flag);
  k_fused5<64, 128, 132, 1, 3><<<(NN / 32) * 3, 256, 0, stream>>>(
      h1, eW1_2, eb1_2, W2s2, ea, ei, src_off, ebs, agg2, flag);
  k_node2<<<NN / 4, 256, 0, stream>>>(agg2, deg_in, h1, root2, bias2, g2, b2,
                                      batch, psum, pcnt, flag);
  k_out<<<(NGR * 64) / 256, 256, 0, stream>>>(psum, pcnt, d_out, flag);
}